// Round 1
// baseline (412.948 us; speedup 1.0000x reference)
//
#include <hip/hip_runtime.h>
#include <math.h>

#define N_NODES 50000
#define N_EDGES 800000
#define IN_DIM 128
#define HEADS 8
#define HEAD_DIM 16
#define OUT_DIM 128
#define NEG_SLOPE 0.2f
#define BN_EPS 1e-5f

// ---- workspace layout (bytes) ----
#define WS_FEAT    0u            // 50000*128 f32 = 25,600,000
#define WS_EL      25600000u     // 50000*8 f32   = 1,600,000
#define WS_ER      27200000u     // 1,600,000
#define WS_OFFS    28800000u     // 50001 ints (pad to 200,064)
#define WS_PART    29000064u     // 256 ints = 1024
#define WS_DEG     29001088u     // 50176 ints = 200,704
#define WS_CURSOR  29201792u     // 50176 ints = 200,704
#define WS_GSUM    29402496u     // 128 f32 = 512
#define WS_GSUMSQ  29403008u     // 128 f32 = 512
#define WS_CSRSRC  29403520u     // 800000 ints = 3,200,000
#define ZERO_START WS_DEG
#define ZERO_INTS  ((WS_CSRSRC - WS_DEG) / 4)   // deg+cursor+gsum+gsumsq

#define NB_SCAN 196              // 196*256 = 50176 >= 50000

__global__ void k_zero(int* __restrict__ p, int n) {
    int i = blockIdx.x * blockDim.x + threadIdx.x;
    if (i < n) p[i] = 0;
}

// GEMM: feat = h @ W  (50000x128 @ 128x128), fused el/er epilogue.
// 32 rows/block, W staged in LDS in two 64-row k-phases (48.9 KB LDS -> 3 blocks/CU).
__global__ __launch_bounds__(256) void k_gemm(
    const float* __restrict__ hin, const float* __restrict__ W,
    const float* __restrict__ attn_l, const float* __restrict__ attn_r,
    float* __restrict__ feat, float* __restrict__ el, float* __restrict__ er)
{
    __shared__ float Ws[64 * 128];    // 32 KB
    __shared__ float Hs[32 * 132];    // 16.9 KB, stride 132 breaks bank conflicts
    const int t = threadIdx.x;
    const int row0 = blockIdx.x * 32;

    // load H tile
    {
        const float4* h4 = (const float4*)hin;
        #pragma unroll
        for (int i = 0; i < 4; i++) {
            int idx = t + 256 * i;          // float4 slot: row = idx/32, col4 = idx%32
            int r = idx >> 5, c4 = idx & 31;
            int gr = row0 + r;
            float4 v = make_float4(0.f, 0.f, 0.f, 0.f);
            if (gr < N_NODES) v = h4[gr * 32 + c4];
            *(float4*)&Hs[r * 132 + c4 * 4] = v;
        }
    }

    float acc[2][8];
    #pragma unroll
    for (int i = 0; i < 2; i++)
        #pragma unroll
        for (int j = 0; j < 8; j++) acc[i][j] = 0.f;

    const int tx = t & 15, ty = t >> 4;
    const int c0 = tx * 8, r0 = ty * 2;

    for (int kp = 0; kp < 2; kp++) {
        __syncthreads();   // Ws safe to overwrite / Hs visible
        {
            const float4* w4 = (const float4*)(W + kp * 64 * 128);
            float4* ws4 = (float4*)Ws;
            #pragma unroll
            for (int i = 0; i < 8; i++) ws4[t + 256 * i] = w4[t + 256 * i];
        }
        __syncthreads();
        const float* hp0 = &Hs[r0 * 132 + kp * 64];
        const float* hp1 = hp0 + 132;
        #pragma unroll 8
        for (int k = 0; k < 64; k++) {
            float a0 = hp0[k], a1 = hp1[k];
            const float* wrow = &Ws[k * 128 + c0];
            float4 b0 = *(const float4*)wrow;
            float4 b1 = *(const float4*)(wrow + 4);
            acc[0][0] += a0 * b0.x; acc[0][1] += a0 * b0.y;
            acc[0][2] += a0 * b0.z; acc[0][3] += a0 * b0.w;
            acc[0][4] += a0 * b1.x; acc[0][5] += a0 * b1.y;
            acc[0][6] += a0 * b1.z; acc[0][7] += a0 * b1.w;
            acc[1][0] += a1 * b0.x; acc[1][1] += a1 * b0.y;
            acc[1][2] += a1 * b0.z; acc[1][3] += a1 * b0.w;
            acc[1][4] += a1 * b1.x; acc[1][5] += a1 * b1.y;
            acc[1][6] += a1 * b1.z; acc[1][7] += a1 * b1.w;
        }
    }

    // el/er epilogue: this thread's 8 cols live in head h = tx>>1
    const int h = tx >> 1;
    const int dbase = (tx & 1) * 8;
    float el0 = 0, el1 = 0, er0 = 0, er1 = 0;
    #pragma unroll
    for (int j = 0; j < 8; j++) {
        float al = attn_l[h * 16 + dbase + j];
        float ar = attn_r[h * 16 + dbase + j];
        el0 += acc[0][j] * al; er0 += acc[0][j] * ar;
        el1 += acc[1][j] * al; er1 += acc[1][j] * ar;
    }
    el0 += __shfl_xor(el0, 1); el1 += __shfl_xor(el1, 1);
    er0 += __shfl_xor(er0, 1); er1 += __shfl_xor(er1, 1);

    int gr0 = row0 + r0;
    if (gr0 < N_NODES) {
        *(float4*)&feat[gr0 * 128 + c0] =
            make_float4(acc[0][0], acc[0][1], acc[0][2], acc[0][3]);
        *(float4*)&feat[gr0 * 128 + c0 + 4] =
            make_float4(acc[0][4], acc[0][5], acc[0][6], acc[0][7]);
        if ((tx & 1) == 0) { el[gr0 * 8 + h] = el0; er[gr0 * 8 + h] = er0; }
    }
    if (gr0 + 1 < N_NODES) {
        *(float4*)&feat[(gr0 + 1) * 128 + c0] =
            make_float4(acc[1][0], acc[1][1], acc[1][2], acc[1][3]);
        *(float4*)&feat[(gr0 + 1) * 128 + c0 + 4] =
            make_float4(acc[1][4], acc[1][5], acc[1][6], acc[1][7]);
        if ((tx & 1) == 0) { el[(gr0 + 1) * 8 + h] = el1; er[(gr0 + 1) * 8 + h] = er1; }
    }
}

__global__ void k_hist(const int* __restrict__ dst, int* __restrict__ deg) {
    int i = blockIdx.x * blockDim.x + threadIdx.x;
    if (i < N_EDGES) atomicAdd(&deg[dst[i]], 1);
}

__global__ __launch_bounds__(256) void k_scan1(const int* __restrict__ deg,
                                               int* __restrict__ partial) {
    int t = threadIdx.x, b = blockIdx.x;
    int v = deg[b * 256 + t];           // zero-padded to 50176
    #pragma unroll
    for (int o = 32; o > 0; o >>= 1) v += __shfl_down(v, o);
    __shared__ int lsum[4];
    if ((t & 63) == 0) lsum[t >> 6] = v;
    __syncthreads();
    if (t == 0) partial[b] = lsum[0] + lsum[1] + lsum[2] + lsum[3];
}

__global__ __launch_bounds__(256) void k_scan2(int* __restrict__ partial,
                                               int* __restrict__ offsets) {
    __shared__ int buf[2][256];
    int t = threadIdx.x;
    int x = (t < NB_SCAN) ? partial[t] : 0;
    buf[0][t] = x;
    __syncthreads();
    int pi = 0;
    for (int o = 1; o < 256; o <<= 1) {
        int v = buf[pi][t] + ((t >= o) ? buf[pi][t - o] : 0);
        buf[pi ^ 1][t] = v; pi ^= 1;
        __syncthreads();
    }
    int incl = buf[pi][t];
    partial[t] = incl - x;              // exclusive prefix of block sums
    if (t == 255) offsets[N_NODES] = incl;   // total = N_EDGES
}

__global__ __launch_bounds__(256) void k_scan3(const int* __restrict__ deg,
                                               const int* __restrict__ partial,
                                               int* __restrict__ offsets) {
    __shared__ int buf[2][256];
    int t = threadIdx.x, b = blockIdx.x;
    int i = b * 256 + t;
    int x = deg[i];
    buf[0][t] = x;
    __syncthreads();
    int pi = 0;
    for (int o = 1; o < 256; o <<= 1) {
        int v = buf[pi][t] + ((t >= o) ? buf[pi][t - o] : 0);
        buf[pi ^ 1][t] = v; pi ^= 1;
        __syncthreads();
    }
    int excl = buf[pi][t] - x + partial[b];
    if (i < N_NODES) offsets[i] = excl;
}

__global__ void k_scatter(const int* __restrict__ src, const int* __restrict__ dst,
                          const int* __restrict__ offsets, int* __restrict__ cursor,
                          int* __restrict__ csr_src) {
    int i = blockIdx.x * blockDim.x + threadIdx.x;
    if (i < N_EDGES) {
        int d = dst[i];
        int pos = offsets[d] + atomicAdd(&cursor[d], 1);
        csr_src[pos] = src[i];
    }
}

// Fused edge-softmax + aggregation: one wave per dst node.
// lane l owns output dims {2l, 2l+1}; head h = l>>3 (8 lanes per head).
__global__ __launch_bounds__(256) void k_agg(
    const float* __restrict__ feat, const float* __restrict__ el,
    const float* __restrict__ er, const int* __restrict__ offsets,
    const int* __restrict__ csr_src, float* __restrict__ outf)
{
    int n = (blockIdx.x * blockDim.x + threadIdx.x) >> 6;   // node = global wave id
    int lane = threadIdx.x & 63;
    if (n >= N_NODES) return;
    int h = lane >> 3;
    int start = offsets[n], end = offsets[n + 1];
    float er_nh = er[n * 8 + h];

    float m = -INFINITY, sum = 0.f;
    for (int p = start; p < end; p++) {
        int s = csr_src[p];
        float e = el[s * 8 + h] + er_nh;
        e = e > 0.f ? e : NEG_SLOPE * e;
        float mn = fmaxf(m, e);
        sum = sum * __expf(m - mn) + __expf(e - mn);
        m = mn;
    }
    float rden = 1.f / sum;

    float2 acc = make_float2(0.f, 0.f);
    const float2* feat2 = (const float2*)feat;
    for (int p = start; p < end; p++) {
        int s = csr_src[p];
        float e = el[s * 8 + h] + er_nh;
        e = e > 0.f ? e : NEG_SLOPE * e;
        float a = __expf(e - m) * rden;
        float2 f = feat2[s * 64 + lane];
        acc.x += a * f.x;
        acc.y += a * f.y;
    }
    ((float2*)outf)[n * 64 + lane] = acc;
}

// BN reduction: per-channel sum & sumsq over 50000 rows.
__global__ __launch_bounds__(256) void k_bnred(const float* __restrict__ outf,
                                               float* __restrict__ gsum,
                                               float* __restrict__ gsumsq) {
    int t = threadIdx.x, b = blockIdx.x;
    int c = t & 127, half = t >> 7;
    const int rows_per = (N_NODES + 255) / 256;   // 196
    int r0 = b * rows_per;
    int r1 = r0 + rows_per; if (r1 > N_NODES) r1 = N_NODES;
    float s = 0.f, s2 = 0.f;
    for (int r = r0 + half; r < r1; r += 2) {
        float v = outf[r * 128 + c];
        s += v; s2 += v * v;
    }
    __shared__ float ls[128], ls2[128];
    if (half == 1) { ls[c] = s; ls2[c] = s2; }
    __syncthreads();
    if (half == 0) {
        s += ls[c]; s2 += ls2[c];
        atomicAdd(&gsum[c], s);
        atomicAdd(&gsumsq[c], s2);
    }
}

// BN normalize + ELU + residual, in place on d_out. float4 per thread.
__global__ __launch_bounds__(256) void k_final(
    const float* __restrict__ hin, const float* __restrict__ gsum,
    const float* __restrict__ gsumsq, const float* __restrict__ gamma,
    const float* __restrict__ beta, float* __restrict__ out)
{
    int i = blockIdx.x * blockDim.x + threadIdx.x;   // float4 index
    if (i >= N_NODES * 32) return;
    int c4 = i & 31;
    float4 x  = ((const float4*)out)[i];
    float4 hv = ((const float4*)hin)[i];
    float4 sm = ((const float4*)gsum)[c4];
    float4 sq = ((const float4*)gsumsq)[c4];
    float4 g  = ((const float4*)gamma)[c4];
    float4 bt = ((const float4*)beta)[c4];
    const float invN = 1.0f / (float)N_NODES;

    float mean, var, rstd, y;
    mean = sm.x * invN; var = sq.x * invN - mean * mean; rstd = rsqrtf(var + BN_EPS);
    y = g.x * (x.x - mean) * rstd + bt.x; y = y > 0.f ? y : (__expf(y) - 1.f); x.x = hv.x + y;
    mean = sm.y * invN; var = sq.y * invN - mean * mean; rstd = rsqrtf(var + BN_EPS);
    y = g.y * (x.y - mean) * rstd + bt.y; y = y > 0.f ? y : (__expf(y) - 1.f); x.y = hv.y + y;
    mean = sm.z * invN; var = sq.z * invN - mean * mean; rstd = rsqrtf(var + BN_EPS);
    y = g.z * (x.z - mean) * rstd + bt.z; y = y > 0.f ? y : (__expf(y) - 1.f); x.z = hv.z + y;
    mean = sm.w * invN; var = sq.w * invN - mean * mean; rstd = rsqrtf(var + BN_EPS);
    y = g.w * (x.w - mean) * rstd + bt.w; y = y > 0.f ? y : (__expf(y) - 1.f); x.w = hv.w + y;

    ((float4*)out)[i] = x;
}

extern "C" void kernel_launch(void* const* d_in, const int* in_sizes, int n_in,
                              void* d_out, int out_size, void* d_ws, size_t ws_size,
                              hipStream_t stream)
{
    const float* hin    = (const float*)d_in[0];
    const int*   src    = (const int*)d_in[1];
    const int*   dst    = (const int*)d_in[2];
    const float* W      = (const float*)d_in[3];
    const float* attn_l = (const float*)d_in[4];
    const float* attn_r = (const float*)d_in[5];
    const float* gamma  = (const float*)d_in[6];
    const float* beta   = (const float*)d_in[7];
    float* out = (float*)d_out;

    char* ws = (char*)d_ws;
    float* feat    = (float*)(ws + WS_FEAT);
    float* el      = (float*)(ws + WS_EL);
    float* er      = (float*)(ws + WS_ER);
    int*   offsets = (int*)(ws + WS_OFFS);
    int*   partial = (int*)(ws + WS_PART);
    int*   deg     = (int*)(ws + WS_DEG);
    int*   cursor  = (int*)(ws + WS_CURSOR);
    float* gsum    = (float*)(ws + WS_GSUM);
    float* gsumsq  = (float*)(ws + WS_GSUMSQ);
    int*   csr     = (int*)(ws + WS_CSRSRC);

    k_zero<<<(ZERO_INTS + 255) / 256, 256, 0, stream>>>((int*)(ws + ZERO_START), ZERO_INTS);
    k_gemm<<<(N_NODES + 31) / 32, 256, 0, stream>>>(hin, W, attn_l, attn_r, feat, el, er);
    k_hist<<<(N_EDGES + 255) / 256, 256, 0, stream>>>(dst, deg);
    k_scan1<<<NB_SCAN, 256, 0, stream>>>(deg, partial);
    k_scan2<<<1, 256, 0, stream>>>(partial, offsets);
    k_scan3<<<NB_SCAN, 256, 0, stream>>>(deg, partial, offsets);
    k_scatter<<<(N_EDGES + 255) / 256, 256, 0, stream>>>(src, dst, offsets, cursor, csr);
    k_agg<<<(N_NODES * 64) / 256, 256, 0, stream>>>(feat, el, er, offsets, csr, out);
    k_bnred<<<256, 256, 0, stream>>>(out, gsum, gsumsq);
    k_final<<<(N_NODES * 32) / 256, 256, 0, stream>>>(hin, gsum, gsumsq, gamma, beta, out);
}

// Round 2
// 324.184 us; speedup vs baseline: 1.2738x; 1.2738x over previous
//
#include <hip/hip_runtime.h>
#include <math.h>

#define N_NODES 50000
#define N_EDGES 800000
#define IN_DIM 128
#define HEADS 8
#define HEAD_DIM 16
#define OUT_DIM 128
#define NEG_SLOPE 0.2f
#define BN_EPS 1e-5f

// ---- workspace layout (bytes) ----
#define WS_FEAT    0u            // 50000*128 f32 = 25,600,000
#define WS_EL      25600000u     // 50000*8 f32   = 1,600,000
#define WS_ER      27200000u     // 1,600,000
#define WS_OFFS    28800000u     // 50001 ints (pad to 200,064)
#define WS_PART    29000064u     // 256 ints = 1024
#define WS_DEG     29001088u     // 50176 ints = 200,704
#define WS_CURSOR  29201792u     // 50176 ints = 200,704
#define WS_GSUM    29402496u     // 128 f32 = 512
#define WS_GSUMSQ  29403008u     // 128 f32 = 512
#define WS_CSRSRC  29403520u     // 800000 ints = 3,200,000
#define WS_AE      32603520u     // 800000*8 f32 = 25,600,000  (ends 58,203,520)
#define ZERO_START WS_DEG
#define ZERO_INTS  ((WS_CSRSRC - WS_DEG) / 4)   // deg+cursor+gsum+gsumsq

#define NB_SCAN 196              // 196*256 = 50176 >= 50000

__device__ __forceinline__ float lrexp(float e) {
    e = e > 0.f ? e : NEG_SLOPE * e;
    return __expf(e);
}

__global__ void k_zero(int* __restrict__ p, int n) {
    int i = blockIdx.x * blockDim.x + threadIdx.x;
    if (i < n) p[i] = 0;
}

// GEMM: feat = h @ W  (50000x128 @ 128x128), fused el/er epilogue.
__global__ __launch_bounds__(256) void k_gemm(
    const float* __restrict__ hin, const float* __restrict__ W,
    const float* __restrict__ attn_l, const float* __restrict__ attn_r,
    float* __restrict__ feat, float* __restrict__ el, float* __restrict__ er)
{
    __shared__ float Ws[64 * 128];    // 32 KB
    __shared__ float Hs[32 * 132];    // 16.9 KB
    const int t = threadIdx.x;
    const int row0 = blockIdx.x * 32;

    {
        const float4* h4 = (const float4*)hin;
        #pragma unroll
        for (int i = 0; i < 4; i++) {
            int idx = t + 256 * i;
            int r = idx >> 5, c4 = idx & 31;
            int gr = row0 + r;
            float4 v = make_float4(0.f, 0.f, 0.f, 0.f);
            if (gr < N_NODES) v = h4[gr * 32 + c4];
            *(float4*)&Hs[r * 132 + c4 * 4] = v;
        }
    }

    float acc[2][8];
    #pragma unroll
    for (int i = 0; i < 2; i++)
        #pragma unroll
        for (int j = 0; j < 8; j++) acc[i][j] = 0.f;

    const int tx = t & 15, ty = t >> 4;
    const int c0 = tx * 8, r0 = ty * 2;

    for (int kp = 0; kp < 2; kp++) {
        __syncthreads();
        {
            const float4* w4 = (const float4*)(W + kp * 64 * 128);
            float4* ws4 = (float4*)Ws;
            #pragma unroll
            for (int i = 0; i < 8; i++) ws4[t + 256 * i] = w4[t + 256 * i];
        }
        __syncthreads();
        const float* hp0 = &Hs[r0 * 132 + kp * 64];
        const float* hp1 = hp0 + 132;
        #pragma unroll 8
        for (int k = 0; k < 64; k++) {
            float a0 = hp0[k], a1 = hp1[k];
            const float* wrow = &Ws[k * 128 + c0];
            float4 b0 = *(const float4*)wrow;
            float4 b1 = *(const float4*)(wrow + 4);
            acc[0][0] += a0 * b0.x; acc[0][1] += a0 * b0.y;
            acc[0][2] += a0 * b0.z; acc[0][3] += a0 * b0.w;
            acc[0][4] += a0 * b1.x; acc[0][5] += a0 * b1.y;
            acc[0][6] += a0 * b1.z; acc[0][7] += a0 * b1.w;
            acc[1][0] += a1 * b0.x; acc[1][1] += a1 * b0.y;
            acc[1][2] += a1 * b0.z; acc[1][3] += a1 * b0.w;
            acc[1][4] += a1 * b1.x; acc[1][5] += a1 * b1.y;
            acc[1][6] += a1 * b1.z; acc[1][7] += a1 * b1.w;
        }
    }

    const int h = tx >> 1;
    const int dbase = (tx & 1) * 8;
    float el0 = 0, el1 = 0, er0 = 0, er1 = 0;
    #pragma unroll
    for (int j = 0; j < 8; j++) {
        float al = attn_l[h * 16 + dbase + j];
        float ar = attn_r[h * 16 + dbase + j];
        el0 += acc[0][j] * al; er0 += acc[0][j] * ar;
        el1 += acc[1][j] * al; er1 += acc[1][j] * ar;
    }
    el0 += __shfl_xor(el0, 1); el1 += __shfl_xor(el1, 1);
    er0 += __shfl_xor(er0, 1); er1 += __shfl_xor(er1, 1);

    int gr0 = row0 + r0;
    if (gr0 < N_NODES) {
        *(float4*)&feat[gr0 * 128 + c0] =
            make_float4(acc[0][0], acc[0][1], acc[0][2], acc[0][3]);
        *(float4*)&feat[gr0 * 128 + c0 + 4] =
            make_float4(acc[0][4], acc[0][5], acc[0][6], acc[0][7]);
        if ((tx & 1) == 0) { el[gr0 * 8 + h] = el0; er[gr0 * 8 + h] = er0; }
    }
    if (gr0 + 1 < N_NODES) {
        *(float4*)&feat[(gr0 + 1) * 128 + c0] =
            make_float4(acc[1][0], acc[1][1], acc[1][2], acc[1][3]);
        *(float4*)&feat[(gr0 + 1) * 128 + c0 + 4] =
            make_float4(acc[1][4], acc[1][5], acc[1][6], acc[1][7]);
        if ((tx & 1) == 0) { el[(gr0 + 1) * 8 + h] = el1; er[(gr0 + 1) * 8 + h] = er1; }
    }
}

__global__ void k_hist(const int* __restrict__ dst, int* __restrict__ deg) {
    int i = blockIdx.x * blockDim.x + threadIdx.x;
    if (i < N_EDGES) atomicAdd(&deg[dst[i]], 1);
}

__global__ __launch_bounds__(256) void k_scan1(const int* __restrict__ deg,
                                               int* __restrict__ partial) {
    int t = threadIdx.x, b = blockIdx.x;
    int v = deg[b * 256 + t];
    #pragma unroll
    for (int o = 32; o > 0; o >>= 1) v += __shfl_down(v, o);
    __shared__ int lsum[4];
    if ((t & 63) == 0) lsum[t >> 6] = v;
    __syncthreads();
    if (t == 0) partial[b] = lsum[0] + lsum[1] + lsum[2] + lsum[3];
}

__global__ __launch_bounds__(256) void k_scan2(int* __restrict__ partial,
                                               int* __restrict__ offsets) {
    __shared__ int buf[2][256];
    int t = threadIdx.x;
    int x = (t < NB_SCAN) ? partial[t] : 0;
    buf[0][t] = x;
    __syncthreads();
    int pi = 0;
    for (int o = 1; o < 256; o <<= 1) {
        int v = buf[pi][t] + ((t >= o) ? buf[pi][t - o] : 0);
        buf[pi ^ 1][t] = v; pi ^= 1;
        __syncthreads();
    }
    int incl = buf[pi][t];
    partial[t] = incl - x;
    if (t == 255) offsets[N_NODES] = incl;
}

__global__ __launch_bounds__(256) void k_scan3(const int* __restrict__ deg,
                                               const int* __restrict__ partial,
                                               int* __restrict__ offsets) {
    __shared__ int buf[2][256];
    int t = threadIdx.x, b = blockIdx.x;
    int i = b * 256 + t;
    int x = deg[i];
    buf[0][t] = x;
    __syncthreads();
    int pi = 0;
    for (int o = 1; o < 256; o <<= 1) {
        int v = buf[pi][t] + ((t >= o) ? buf[pi][t - o] : 0);
        buf[pi ^ 1][t] = v; pi ^= 1;
        __syncthreads();
    }
    int excl = buf[pi][t] - x + partial[b];
    if (i < N_NODES) offsets[i] = excl;
}

// CSR scatter fused with per-edge attention numerator:
// ae[pos*8+h] = exp(leakyrelu(el[src,h] + er[dst,h]))
__global__ __launch_bounds__(256) void k_scatter(
    const int* __restrict__ src, const int* __restrict__ dst,
    const int* __restrict__ offsets, int* __restrict__ cursor,
    const float* __restrict__ el, const float* __restrict__ er,
    int* __restrict__ csr_src, float* __restrict__ ae_csr)
{
    int i = blockIdx.x * blockDim.x + threadIdx.x;
    if (i >= N_EDGES) return;
    int s = src[i], d = dst[i];
    int pos = offsets[d] + atomicAdd(&cursor[d], 1);
    csr_src[pos] = s;
    float4 l0 = *(const float4*)&el[s * 8];
    float4 l1 = *(const float4*)&el[s * 8 + 4];
    float4 r0 = *(const float4*)&er[d * 8];
    float4 r1 = *(const float4*)&er[d * 8 + 4];
    float4 o0, o1;
    o0.x = lrexp(l0.x + r0.x); o0.y = lrexp(l0.y + r0.y);
    o0.z = lrexp(l0.z + r0.z); o0.w = lrexp(l0.w + r0.w);
    o1.x = lrexp(l1.x + r1.x); o1.y = lrexp(l1.y + r1.y);
    o1.z = lrexp(l1.z + r1.z); o1.w = lrexp(l1.w + r1.w);
    float* dst_ae = &ae_csr[(size_t)pos * 8];
    *(float4*)dst_ae = o0;
    *(float4*)(dst_ae + 4) = o1;
}

// Fused single-pass softmax-aggregate: one wave per dst node.
// lane l owns output dims {2l, 2l+1}; head h = l>>3.
// out = (sum ae*feat[src]) / (sum ae)   -- identical to max-shifted softmax.
__global__ __launch_bounds__(256) void k_agg(
    const float* __restrict__ feat, const float* __restrict__ ae_csr,
    const int* __restrict__ offsets, const int* __restrict__ csr_src,
    float* __restrict__ outf)
{
    int n = (blockIdx.x * blockDim.x + threadIdx.x) >> 6;
    int lane = threadIdx.x & 63;
    if (n >= N_NODES) return;
    int h = lane >> 3;
    int start = offsets[n], end = offsets[n + 1];
    const float2* feat2 = (const float2*)feat;

    float sum = 0.f, ax = 0.f, ay = 0.f;
    int p = start;
    for (; p + 4 <= end; p += 4) {
        int s0 = csr_src[p + 0], s1 = csr_src[p + 1];
        int s2 = csr_src[p + 2], s3 = csr_src[p + 3];
        float a0 = ae_csr[(size_t)(p + 0) * 8 + h];
        float a1 = ae_csr[(size_t)(p + 1) * 8 + h];
        float a2 = ae_csr[(size_t)(p + 2) * 8 + h];
        float a3 = ae_csr[(size_t)(p + 3) * 8 + h];
        float2 f0 = feat2[s0 * 64 + lane];
        float2 f1 = feat2[s1 * 64 + lane];
        float2 f2 = feat2[s2 * 64 + lane];
        float2 f3 = feat2[s3 * 64 + lane];
        sum += (a0 + a1) + (a2 + a3);
        ax += a0 * f0.x; ay += a0 * f0.y;
        ax += a1 * f1.x; ay += a1 * f1.y;
        ax += a2 * f2.x; ay += a2 * f2.y;
        ax += a3 * f3.x; ay += a3 * f3.y;
    }
    for (; p < end; p++) {
        int s = csr_src[p];
        float a = ae_csr[(size_t)p * 8 + h];
        float2 f = feat2[s * 64 + lane];
        sum += a; ax += a * f.x; ay += a * f.y;
    }
    float rden = sum > 0.f ? 1.f / sum : 0.f;   // deg-0 node -> 0 (matches ref)
    ((float2*)outf)[n * 64 + lane] = make_float2(ax * rden, ay * rden);
}

__global__ __launch_bounds__(256) void k_bnred(const float* __restrict__ outf,
                                               float* __restrict__ gsum,
                                               float* __restrict__ gsumsq) {
    int t = threadIdx.x, b = blockIdx.x;
    int c = t & 127, half = t >> 7;
    const int rows_per = (N_NODES + 255) / 256;
    int r0 = b * rows_per;
    int r1 = r0 + rows_per; if (r1 > N_NODES) r1 = N_NODES;
    float s = 0.f, s2 = 0.f;
    for (int r = r0 + half; r < r1; r += 2) {
        float v = outf[r * 128 + c];
        s += v; s2 += v * v;
    }
    __shared__ float ls[128], ls2[128];
    if (half == 1) { ls[c] = s; ls2[c] = s2; }
    __syncthreads();
    if (half == 0) {
        s += ls[c]; s2 += ls2[c];
        atomicAdd(&gsum[c], s);
        atomicAdd(&gsumsq[c], s2);
    }
}

__global__ __launch_bounds__(256) void k_final(
    const float* __restrict__ hin, const float* __restrict__ gsum,
    const float* __restrict__ gsumsq, const float* __restrict__ gamma,
    const float* __restrict__ beta, float* __restrict__ out)
{
    int i = blockIdx.x * blockDim.x + threadIdx.x;
    if (i >= N_NODES * 32) return;
    int c4 = i & 31;
    float4 x  = ((const float4*)out)[i];
    float4 hv = ((const float4*)hin)[i];
    float4 sm = ((const float4*)gsum)[c4];
    float4 sq = ((const float4*)gsumsq)[c4];
    float4 g  = ((const float4*)gamma)[c4];
    float4 bt = ((const float4*)beta)[c4];
    const float invN = 1.0f / (float)N_NODES;

    float mean, var, rstd, y;
    mean = sm.x * invN; var = sq.x * invN - mean * mean; rstd = rsqrtf(var + BN_EPS);
    y = g.x * (x.x - mean) * rstd + bt.x; y = y > 0.f ? y : (__expf(y) - 1.f); x.x = hv.x + y;
    mean = sm.y * invN; var = sq.y * invN - mean * mean; rstd = rsqrtf(var + BN_EPS);
    y = g.y * (x.y - mean) * rstd + bt.y; y = y > 0.f ? y : (__expf(y) - 1.f); x.y = hv.y + y;
    mean = sm.z * invN; var = sq.z * invN - mean * mean; rstd = rsqrtf(var + BN_EPS);
    y = g.z * (x.z - mean) * rstd + bt.z; y = y > 0.f ? y : (__expf(y) - 1.f); x.z = hv.z + y;
    mean = sm.w * invN; var = sq.w * invN - mean * mean; rstd = rsqrtf(var + BN_EPS);
    y = g.w * (x.w - mean) * rstd + bt.w; y = y > 0.f ? y : (__expf(y) - 1.f); x.w = hv.w + y;

    ((float4*)out)[i] = x;
}

extern "C" void kernel_launch(void* const* d_in, const int* in_sizes, int n_in,
                              void* d_out, int out_size, void* d_ws, size_t ws_size,
                              hipStream_t stream)
{
    const float* hin    = (const float*)d_in[0];
    const int*   src    = (const int*)d_in[1];
    const int*   dst    = (const int*)d_in[2];
    const float* W      = (const float*)d_in[3];
    const float* attn_l = (const float*)d_in[4];
    const float* attn_r = (const float*)d_in[5];
    const float* gamma  = (const float*)d_in[6];
    const float* beta   = (const float*)d_in[7];
    float* out = (float*)d_out;

    char* ws = (char*)d_ws;
    float* feat    = (float*)(ws + WS_FEAT);
    float* el      = (float*)(ws + WS_EL);
    float* er      = (float*)(ws + WS_ER);
    int*   offsets = (int*)(ws + WS_OFFS);
    int*   partial = (int*)(ws + WS_PART);
    int*   deg     = (int*)(ws + WS_DEG);
    int*   cursor  = (int*)(ws + WS_CURSOR);
    float* gsum    = (float*)(ws + WS_GSUM);
    float* gsumsq  = (float*)(ws + WS_GSUMSQ);
    int*   csr     = (int*)(ws + WS_CSRSRC);
    float* ae      = (float*)(ws + WS_AE);

    k_zero<<<(ZERO_INTS + 255) / 256, 256, 0, stream>>>((int*)(ws + ZERO_START), ZERO_INTS);
    k_gemm<<<(N_NODES + 31) / 32, 256, 0, stream>>>(hin, W, attn_l, attn_r, feat, el, er);
    k_hist<<<(N_EDGES + 255) / 256, 256, 0, stream>>>(dst, deg);
    k_scan1<<<NB_SCAN, 256, 0, stream>>>(deg, partial);
    k_scan2<<<1, 256, 0, stream>>>(partial, offsets);
    k_scan3<<<NB_SCAN, 256, 0, stream>>>(deg, partial, offsets);
    k_scatter<<<(N_EDGES + 255) / 256, 256, 0, stream>>>(src, dst, offsets, cursor,
                                                         el, er, csr, ae);
    k_agg<<<(N_NODES * 64) / 256, 256, 0, stream>>>(feat, ae, offsets, csr, out);
    k_bnred<<<256, 256, 0, stream>>>(out, gsum, gsumsq);
    k_final<<<(N_NODES * 32) / 256, 256, 0, stream>>>(hin, gsum, gsumsq, gamma, beta, out);
}

// Round 3
// 298.821 us; speedup vs baseline: 1.3819x; 1.0849x over previous
//
#include <hip/hip_runtime.h>
#include <math.h>

#define N_NODES 50000
#define N_EDGES 800000
#define IN_DIM 128
#define HEADS 8
#define HEAD_DIM 16
#define OUT_DIM 128
#define NEG_SLOPE 0.2f
#define BN_EPS 1e-5f

// ---- workspace layout (bytes) ----
#define WS_FEAT    0u            // 50000*128 f32 = 25,600,000
#define WS_EL      25600000u     // 50000*8 f32   = 1,600,000
#define WS_ER      27200000u     // 1,600,000
#define WS_OFFS    28800000u     // 50001 ints (pad to 200,064)
#define WS_PART    29000064u     // 256 ints
#define WS_DEG     29001088u     // 50176 ints = 200,704
#define WS_CURSOR  29201792u     // 50176 ints = 200,704
#define WS_GSUM    29402496u     // 128 f32
#define WS_GSUMSQ  29403008u     // 128 f32
#define WS_CSRSRC  29403520u     // 800000 ints = 3,200,000
#define ZERO_START WS_DEG
#define ZERO_BYTES (WS_CSRSRC - WS_DEG)   // deg+cursor+gsum+gsumsq

#define NB_SCAN 196              // 196*256 = 50176 >= 50000
#define GEMM_BLOCKS 782          // ceil(50000/64)
#define HIST_BLOCKS 3125         // 800000/256

// ---------------------------------------------------------------------------
// Fused GEMM (feat = h @ W, 64-row tiles, W from L2) + el/er epilogue,
// with histogram blocks appended to the same launch.
// ---------------------------------------------------------------------------
__global__ __launch_bounds__(256) void k_main(
    const float* __restrict__ hin, const float* __restrict__ W,
    const float* __restrict__ attn_l, const float* __restrict__ attn_r,
    const int* __restrict__ dst, int* __restrict__ deg,
    float* __restrict__ feat, float* __restrict__ el, float* __restrict__ er)
{
    if (blockIdx.x >= GEMM_BLOCKS) {
        // histogram part
        int i = (blockIdx.x - GEMM_BLOCKS) * 256 + threadIdx.x;
        if (i < N_EDGES) atomicAdd(&deg[dst[i]], 1);
        return;
    }

    __shared__ float Hs[64 * 132];   // stride 132: float4-aligned, 2-way banks only
    const int t = threadIdx.x;
    const int row0 = blockIdx.x * 64;

    {   // load 64x128 H tile as float4 (8 per thread)
        const float4* h4 = (const float4*)hin;
        #pragma unroll
        for (int i = 0; i < 8; i++) {
            int idx = t + 256 * i;            // 0..2047
            int r = idx >> 5, c4 = idx & 31;
            int gr = row0 + r;
            float4 v = make_float4(0.f, 0.f, 0.f, 0.f);
            if (gr < N_NODES) v = h4[gr * 32 + c4];
            *(float4*)&Hs[r * 132 + c4 * 4] = v;
        }
    }
    __syncthreads();

    const int tx = t & 15, ty = t >> 4;
    const int c0 = tx * 8, r0 = ty * 4;

    float acc[4][8];
    #pragma unroll
    for (int r = 0; r < 4; r++)
        #pragma unroll
        for (int j = 0; j < 8; j++) acc[r][j] = 0.f;

    const float4* W4 = (const float4*)W;      // [128][32] float4, L2-resident
    const float4* A0 = (const float4*)&Hs[(r0 + 0) * 132];
    const float4* A1 = (const float4*)&Hs[(r0 + 1) * 132];
    const float4* A2 = (const float4*)&Hs[(r0 + 2) * 132];
    const float4* A3 = (const float4*)&Hs[(r0 + 3) * 132];

    #pragma unroll 2
    for (int k4 = 0; k4 < 32; k4++) {         // K=128 in chunks of 4
        float4 a0 = A0[k4], a1 = A1[k4], a2 = A2[k4], a3 = A3[k4];
        float Av0[4] = {a0.x, a0.y, a0.z, a0.w};
        float Av1[4] = {a1.x, a1.y, a1.z, a1.w};
        float Av2[4] = {a2.x, a2.y, a2.z, a2.w};
        float Av3[4] = {a3.x, a3.y, a3.z, a3.w};
        int kb = k4 * 4;
        #pragma unroll
        for (int kk = 0; kk < 4; kk++) {
            float4 b0 = W4[(kb + kk) * 32 + tx * 2];
            float4 b1 = W4[(kb + kk) * 32 + tx * 2 + 1];
            float av[4] = {Av0[kk], Av1[kk], Av2[kk], Av3[kk]};
            #pragma unroll
            for (int r = 0; r < 4; r++) {
                acc[r][0] += av[r] * b0.x; acc[r][1] += av[r] * b0.y;
                acc[r][2] += av[r] * b0.z; acc[r][3] += av[r] * b0.w;
                acc[r][4] += av[r] * b1.x; acc[r][5] += av[r] * b1.y;
                acc[r][6] += av[r] * b1.z; acc[r][7] += av[r] * b1.w;
            }
        }
    }

    // el/er epilogue: cols c0..c0+7 live in head h = tx>>1, half dbase
    const int h = tx >> 1;
    const int dbase = (tx & 1) * 8;
    float elv[4], erv[4];
    #pragma unroll
    for (int r = 0; r < 4; r++) {
        float e = 0.f, f = 0.f;
        #pragma unroll
        for (int j = 0; j < 8; j++) {
            float al = attn_l[h * 16 + dbase + j];
            float ar = attn_r[h * 16 + dbase + j];
            e += acc[r][j] * al; f += acc[r][j] * ar;
        }
        elv[r] = e + __shfl_xor(e, 1);
        erv[r] = f + __shfl_xor(f, 1);
    }

    #pragma unroll
    for (int r = 0; r < 4; r++) {
        int gr = row0 + r0 + r;
        if (gr < N_NODES) {
            *(float4*)&feat[gr * 128 + c0] =
                make_float4(acc[r][0], acc[r][1], acc[r][2], acc[r][3]);
            *(float4*)&feat[gr * 128 + c0 + 4] =
                make_float4(acc[r][4], acc[r][5], acc[r][6], acc[r][7]);
            if ((tx & 1) == 0) { el[gr * 8 + h] = elv[r]; er[gr * 8 + h] = erv[r]; }
        }
    }
}

// ---------------------------------------------------------------------------
// Single-kernel exclusive scan of deg -> offsets (196 blocks).
// Each block redundantly sums preceding blocks (L2-resident, cheap).
// ---------------------------------------------------------------------------
__global__ __launch_bounds__(256) void k_scan(const int* __restrict__ deg,
                                              int* __restrict__ offsets)
{
    int t = threadIdx.x, b = blockIdx.x;

    int pre = 0;
    if (t < b) {
        const int4* d4 = (const int4*)(deg + t * 256);
        #pragma unroll 8
        for (int j = 0; j < 64; j++) {
            int4 v = d4[j];
            pre += v.x + v.y + v.z + v.w;
        }
    }
    __shared__ int red[256];
    red[t] = pre;
    __syncthreads();
    #pragma unroll
    for (int o = 128; o > 0; o >>= 1) {
        if (t < o) red[t] += red[t + o];
        __syncthreads();
    }
    int base = red[0];

    __shared__ int buf[2][256];
    int i = b * 256 + t;
    int x = deg[i];                     // zero-padded to 50176
    buf[0][t] = x;
    __syncthreads();
    int pi = 0;
    for (int o = 1; o < 256; o <<= 1) {
        int v = buf[pi][t] + ((t >= o) ? buf[pi][t - o] : 0);
        buf[pi ^ 1][t] = v; pi ^= 1;
        __syncthreads();
    }
    int incl = buf[pi][t];
    if (i < N_NODES) offsets[i] = incl - x + base;
    if (b == NB_SCAN - 1 && t == 255) offsets[N_NODES] = incl + base;
}

// ---------------------------------------------------------------------------
// Lean CSR scatter: csr_src[pos] = src for each edge, grouped by dst.
// ---------------------------------------------------------------------------
__global__ void k_scatter(const int* __restrict__ src, const int* __restrict__ dst,
                          const int* __restrict__ offsets, int* __restrict__ cursor,
                          int* __restrict__ csr_src)
{
    int i = blockIdx.x * blockDim.x + threadIdx.x;
    if (i < N_EDGES) {
        int d = dst[i];
        int pos = offsets[d] + atomicAdd(&cursor[d], 1);
        csr_src[pos] = src[i];
    }
}

// ---------------------------------------------------------------------------
// Fused single-pass softmax-aggregate: one wave per dst node.
// lane l owns dims {2l,2l+1}; head h = l>>3. exp computed inline (el/er in L2).
// ---------------------------------------------------------------------------
__global__ __launch_bounds__(256) void k_agg(
    const float* __restrict__ feat, const float* __restrict__ el,
    const float* __restrict__ er, const int* __restrict__ offsets,
    const int* __restrict__ csr_src, float* __restrict__ outf)
{
    int n = (blockIdx.x * blockDim.x + threadIdx.x) >> 6;
    int lane = threadIdx.x & 63;
    if (n >= N_NODES) return;
    int h = lane >> 3;
    int start = offsets[n], end = offsets[n + 1];
    float er_nh = er[n * 8 + h];
    const float2* feat2 = (const float2*)feat;

    float sum = 0.f, ax = 0.f, ay = 0.f;
    int p = start;
    for (; p + 4 <= end; p += 4) {
        int s0 = csr_src[p + 0], s1 = csr_src[p + 1];
        int s2 = csr_src[p + 2], s3 = csr_src[p + 3];
        float e0 = el[s0 * 8 + h] + er_nh;
        float e1 = el[s1 * 8 + h] + er_nh;
        float e2 = el[s2 * 8 + h] + er_nh;
        float e3 = el[s3 * 8 + h] + er_nh;
        e0 = e0 > 0.f ? e0 : NEG_SLOPE * e0;
        e1 = e1 > 0.f ? e1 : NEG_SLOPE * e1;
        e2 = e2 > 0.f ? e2 : NEG_SLOPE * e2;
        e3 = e3 > 0.f ? e3 : NEG_SLOPE * e3;
        float a0 = __expf(e0), a1 = __expf(e1), a2 = __expf(e2), a3 = __expf(e3);
        float2 f0 = feat2[s0 * 64 + lane];
        float2 f1 = feat2[s1 * 64 + lane];
        float2 f2 = feat2[s2 * 64 + lane];
        float2 f3 = feat2[s3 * 64 + lane];
        sum += (a0 + a1) + (a2 + a3);
        ax += a0 * f0.x; ay += a0 * f0.y;
        ax += a1 * f1.x; ay += a1 * f1.y;
        ax += a2 * f2.x; ay += a2 * f2.y;
        ax += a3 * f3.x; ay += a3 * f3.y;
    }
    for (; p < end; p++) {
        int s = csr_src[p];
        float e = el[s * 8 + h] + er_nh;
        e = e > 0.f ? e : NEG_SLOPE * e;
        float a = __expf(e);
        float2 f = feat2[s * 64 + lane];
        sum += a; ax += a * f.x; ay += a * f.y;
    }
    float rden = sum > 0.f ? 1.f / sum : 0.f;
    ((float2*)outf)[n * 64 + lane] = make_float2(ax * rden, ay * rden);
}

__global__ __launch_bounds__(256) void k_bnred(const float* __restrict__ outf,
                                               float* __restrict__ gsum,
                                               float* __restrict__ gsumsq) {
    int t = threadIdx.x, b = blockIdx.x;
    int c = t & 127, half = t >> 7;
    const int rows_per = (N_NODES + 255) / 256;
    int r0 = b * rows_per;
    int r1 = r0 + rows_per; if (r1 > N_NODES) r1 = N_NODES;
    float s = 0.f, s2 = 0.f;
    for (int r = r0 + half; r < r1; r += 2) {
        float v = outf[r * 128 + c];
        s += v; s2 += v * v;
    }
    __shared__ float ls[128], ls2[128];
    if (half == 1) { ls[c] = s; ls2[c] = s2; }
    __syncthreads();
    if (half == 0) {
        s += ls[c]; s2 += ls2[c];
        atomicAdd(&gsum[c], s);
        atomicAdd(&gsumsq[c], s2);
    }
}

__global__ __launch_bounds__(256) void k_final(
    const float* __restrict__ hin, const float* __restrict__ gsum,
    const float* __restrict__ gsumsq, const float* __restrict__ gamma,
    const float* __restrict__ beta, float* __restrict__ out)
{
    int i = blockIdx.x * blockDim.x + threadIdx.x;
    if (i >= N_NODES * 32) return;
    int c4 = i & 31;
    float4 x  = ((const float4*)out)[i];
    float4 hv = ((const float4*)hin)[i];
    float4 sm = ((const float4*)gsum)[c4];
    float4 sq = ((const float4*)gsumsq)[c4];
    float4 g  = ((const float4*)gamma)[c4];
    float4 bt = ((const float4*)beta)[c4];
    const float invN = 1.0f / (float)N_NODES;

    float mean, var, rstd, y;
    mean = sm.x * invN; var = sq.x * invN - mean * mean; rstd = rsqrtf(var + BN_EPS);
    y = g.x * (x.x - mean) * rstd + bt.x; y = y > 0.f ? y : (__expf(y) - 1.f); x.x = hv.x + y;
    mean = sm.y * invN; var = sq.y * invN - mean * mean; rstd = rsqrtf(var + BN_EPS);
    y = g.y * (x.y - mean) * rstd + bt.y; y = y > 0.f ? y : (__expf(y) - 1.f); x.y = hv.y + y;
    mean = sm.z * invN; var = sq.z * invN - mean * mean; rstd = rsqrtf(var + BN_EPS);
    y = g.z * (x.z - mean) * rstd + bt.z; y = y > 0.f ? y : (__expf(y) - 1.f); x.z = hv.z + y;
    mean = sm.w * invN; var = sq.w * invN - mean * mean; rstd = rsqrtf(var + BN_EPS);
    y = g.w * (x.w - mean) * rstd + bt.w; y = y > 0.f ? y : (__expf(y) - 1.f); x.w = hv.w + y;

    ((float4*)out)[i] = x;
}

extern "C" void kernel_launch(void* const* d_in, const int* in_sizes, int n_in,
                              void* d_out, int out_size, void* d_ws, size_t ws_size,
                              hipStream_t stream)
{
    const float* hin    = (const float*)d_in[0];
    const int*   src    = (const int*)d_in[1];
    const int*   dst    = (const int*)d_in[2];
    const float* W      = (const float*)d_in[3];
    const float* attn_l = (const float*)d_in[4];
    const float* attn_r = (const float*)d_in[5];
    const float* gamma  = (const float*)d_in[6];
    const float* beta   = (const float*)d_in[7];
    float* out = (float*)d_out;

    char* ws = (char*)d_ws;
    float* feat    = (float*)(ws + WS_FEAT);
    float* el      = (float*)(ws + WS_EL);
    float* er      = (float*)(ws + WS_ER);
    int*   offsets = (int*)(ws + WS_OFFS);
    int*   deg     = (int*)(ws + WS_DEG);
    int*   cursor  = (int*)(ws + WS_CURSOR);
    float* gsum    = (float*)(ws + WS_GSUM);
    float* gsumsq  = (float*)(ws + WS_GSUMSQ);
    int*   csr     = (int*)(ws + WS_CSRSRC);

    hipMemsetAsync(ws + ZERO_START, 0, ZERO_BYTES, stream);
    k_main<<<GEMM_BLOCKS + HIST_BLOCKS, 256, 0, stream>>>(
        hin, W, attn_l, attn_r, dst, deg, feat, el, er);
    k_scan<<<NB_SCAN, 256, 0, stream>>>(deg, offsets);
    k_scatter<<<(N_EDGES + 255) / 256, 256, 0, stream>>>(src, dst, offsets, cursor, csr);
    k_agg<<<(N_NODES * 64) / 256, 256, 0, stream>>>(feat, el, er, offsets, csr, out);
    k_bnred<<<256, 256, 0, stream>>>(out, gsum, gsumsq);
    k_final<<<(N_NODES * 32) / 256, 256, 0, stream>>>(hin, gsum, gsumsq, gamma, beta, out);
}